// Round 2
// baseline (411.279 us; speedup 1.0000x reference)
//
#include <hip/hip_runtime.h>

// VersorRotorRNN: B=16, S=256, N=16, D=6, H=16, 32 blades (Cl(5,0)).
// Segmented parallel scan over S. normalize() is scale-invariant and the
// geometric product is bilinear+associative, so psi_t = N(dr_t (x) ... (x) dr_1)
// with dr unnormalized and all intermediate normalizations optional.
// SEGT segments of L=256/SEGT steps; Kogge-Stone in-wave scan over segments.

#define EPS 1e-8f

// --- compile-time Cayley sign table: sgn(i,j) for C[i,j,i^j] ---
struct SgnTab { float v[32][32]; };
constexpr SgnTab make_sgn() {
    SgnTab t{};
    for (int i = 0; i < 32; ++i)
        for (int j = 0; j < 32; ++j) {
            int a = i >> 1, s = 0;
            while (a) {
                int x = a & j;
                while (x) { s += x & 1; x >>= 1; }
                a >>= 1;
            }
            t.v[i][j] = (s & 1) ? -1.0f : 1.0f;
        }
    return t;
}
__device__ constexpr SgnTab SG = make_sgn();

// dst = a (x) b (raw geometric product). dst may alias a or b.
__device__ __forceinline__ void gp_raw(float* __restrict__ dst,
                                       const float* a, const float* b) {
    float np[32];
#pragma unroll
    for (int k = 0; k < 32; ++k) np[k] = 0.0f;
#pragma unroll
    for (int i = 0; i < 32; ++i) {
#pragma unroll
        for (int j = 0; j < 32; ++j) {
            np[i ^ j] = fmaf(SG.v[i][j] * a[i], b[j], np[i ^ j]);
        }
    }
#pragma unroll
    for (int k = 0; k < 32; ++k) dst[k] = np[k];
}

__device__ __forceinline__ float inv_norm(const float* v) {
    float s0 = 0.f, s1 = 0.f, s2 = 0.f, s3 = 0.f;
#pragma unroll
    for (int k = 0; k < 32; k += 4) {
        s0 = fmaf(v[k],     v[k],     s0);
        s1 = fmaf(v[k + 1], v[k + 1], s1);
        s2 = fmaf(v[k + 2], v[k + 2], s2);
        s3 = fmaf(v[k + 3], v[k + 3], s3);
    }
    return rsqrtf((s0 + s1) + (s2 + s3) + EPS);
}

// ---------------- pass 1: per-segment products -------------------
// thread u: h=u&15, bn=(u>>4)&255, s=u>>12. Normalize ONCE before store.
template <int SEGT>
__global__ __launch_bounds__(256, 2) void k_seg(
        const float* __restrict__ x, const float* __restrict__ W_in,
        const float* __restrict__ b_in, float* __restrict__ Q) {
    constexpr int L = 256 / SEGT;
    __shared__ float WL[3072];  // [(d*32+c)*16 + h] = W_in[d][h*32+c]
    __shared__ float BL[512];   // [c*16 + h]        = b_in[h*32+c]
    const int tid = threadIdx.x;
    for (int idx = tid; idx < 3072; idx += 256) {
        int h = idx & 15, dc = idx >> 4, c = dc & 31, d = dc >> 5;
        WL[idx] = W_in[d * 512 + h * 32 + c];
    }
    for (int idx = tid; idx < 512; idx += 256) {
        int h = idx & 15, c = idx >> 4;
        BL[idx] = b_in[h * 32 + c];
    }
    __syncthreads();

    const unsigned u = blockIdx.x * 256 + tid;
    const int h = u & 15, bn = (u >> 4) & 255, s = u >> 12;
    const int b = bn >> 4, n = bn & 15;
    const float* WLh = WL + h;
    const float* BLh = BL + h;

    float P[32];
    for (int i = 0; i < L; ++i) {
        const int t = s * L + i;
        const float2* xp = (const float2*)(x + ((b * 256 + t) * 16 + n) * 6);
        float2 x01 = xp[0], x23 = xp[1], x45 = xp[2];
        const float xv[6] = {x01.x, x01.y, x23.x, x23.y, x45.x, x45.y};
        float uu[32];
#pragma unroll
        for (int c = 0; c < 32; ++c) uu[c] = BLh[c * 16];
#pragma unroll
        for (int d = 0; d < 6; ++d)
#pragma unroll
            for (int c = 0; c < 32; ++c)
                uu[c] = fmaf(xv[d], WLh[(d * 32 + c) * 16], uu[c]);
        uu[0] += 1.0f;           // delta_r (unnormalized; scale cancels)
        if (i == 0) {
#pragma unroll
            for (int k = 0; k < 32; ++k) P[k] = uu[k];  // 1 (x) u = u
        } else {
            gp_raw(P, uu, P);    // raw; normalize deferred
        }
    }
    float rs = inv_norm(P);
    const int chain = bn * 16 + h;
    float4* qp = (float4*)(Q + (chain * SEGT + s) * 32);
#pragma unroll
    for (int r = 0; r < 8; ++r)
        qp[r] = make_float4(P[4 * r] * rs, P[4 * r + 1] * rs,
                            P[4 * r + 2] * rs, P[4 * r + 3] * rs);
}

// ---------------- pass 2: Kogge-Stone exclusive scan, in-wave ----------
// thread u: s = u & (SEGT-1), chain = u >> log2(SEGT). SEGT lanes per chain.
template <int SEGT>
__global__ __launch_bounds__(256, 2) void k_scan(float* __restrict__ Q) {
    const unsigned u = blockIdx.x * 256 + threadIdx.x;
    const int s = u & (SEGT - 1);
    const unsigned chain = u / SEGT;

    float xr[32];
    {
        const float4* qp = (const float4*)(Q + (chain * SEGT + s) * 32);
#pragma unroll
        for (int r = 0; r < 8; ++r) {
            float4 v = qp[r];
            xr[4 * r] = v.x; xr[4 * r + 1] = v.y;
            xr[4 * r + 2] = v.z; xr[4 * r + 3] = v.w;
        }
    }
#pragma unroll
    for (int k = 1; k < SEGT; k <<= 1) {
        float pr[32];
#pragma unroll
        for (int j = 0; j < 32; ++j) pr[j] = __shfl_up(xr[j], k, SEGT);
        if (s >= k) {
            gp_raw(xr, xr, pr);      // later range on the left
            float rs = inv_norm(xr);
#pragma unroll
            for (int j = 0; j < 32; ++j) xr[j] *= rs;
        }
    }
    // exclusive shift by one within the SEGT-group
    float er[32];
#pragma unroll
    for (int j = 0; j < 32; ++j) er[j] = __shfl_up(xr[j], 1, SEGT);
    if (s == 0) {
#pragma unroll
        for (int j = 0; j < 32; ++j) er[j] = 0.0f;
        er[0] = 1.0f;  // identity rotor
    }
    float4* qp = (float4*)(Q + (chain * SEGT + s) * 32);
#pragma unroll
    for (int r = 0; r < 8; ++r)
        qp[r] = make_float4(er[4 * r], er[4 * r + 1],
                            er[4 * r + 2], er[4 * r + 3]);
}

// ---------------- pass 3: apply interior + project + write output ----------
template <int SEGT>
__global__ __launch_bounds__(256, 2) void k_apply(
        const float* __restrict__ x, const float* __restrict__ W_in,
        const float* __restrict__ b_in, const float* __restrict__ W_out,
        const float* __restrict__ b_out, const float* __restrict__ Pre,
        float* __restrict__ out) {
    constexpr int L = 256 / SEGT;
    __shared__ float WL[3072];  // as in k_seg
    __shared__ float BL[512];
    __shared__ float WO[3072];  // [(k*6+d)*16 + h] = W_out[(h*32+k)*6+d]
    const int tid = threadIdx.x;
    for (int idx = tid; idx < 3072; idx += 256) {
        int h = idx & 15, dc = idx >> 4;
        int c = dc & 31, d = dc >> 5;
        WL[idx] = W_in[d * 512 + h * 32 + c];
        int dd = dc % 6, k = dc / 6;
        WO[idx] = W_out[(h * 32 + k) * 6 + dd];
    }
    for (int idx = tid; idx < 512; idx += 256) {
        int h = idx & 15, c = idx >> 4;
        BL[idx] = b_in[h * 32 + c];
    }
    __syncthreads();

    const unsigned u = blockIdx.x * 256 + tid;
    const int h = u & 15, bn = (u >> 4) & 255, s = u >> 12;
    const int b = bn >> 4, n = bn & 15;
    const int chain = bn * 16 + h;
    const float* WLh = WL + h;
    const float* BLh = BL + h;
    const float* WOh = WO + h;

    float R[32];
    {
        const float4* pp = (const float4*)(Pre + (chain * SEGT + s) * 32);
#pragma unroll
        for (int r = 0; r < 8; ++r) {
            float4 v = pp[r];
            R[4 * r] = v.x; R[4 * r + 1] = v.y;
            R[4 * r + 2] = v.z; R[4 * r + 3] = v.w;
        }
    }
    float bo[6];
#pragma unroll
    for (int d = 0; d < 6; ++d) bo[d] = b_out[d];

    for (int i = 0; i < L; ++i) {
        const int t = s * L + i;
        const float2* xp = (const float2*)(x + ((b * 256 + t) * 16 + n) * 6);
        float2 x01 = xp[0], x23 = xp[1], x45 = xp[2];
        const float xv[6] = {x01.x, x01.y, x23.x, x23.y, x45.x, x45.y};
        float uu[32];
#pragma unroll
        for (int c = 0; c < 32; ++c) uu[c] = BLh[c * 16];
#pragma unroll
        for (int d = 0; d < 6; ++d)
#pragma unroll
            for (int c = 0; c < 32; ++c)
                uu[c] = fmaf(xv[d], WLh[(d * 32 + c) * 16], uu[c]);
        uu[0] += 1.0f;
        gp_raw(R, uu, R);
        float rs = inv_norm(R);
#pragma unroll
        for (int k = 0; k < 32; ++k) R[k] *= rs;  // R = psi_t (normalized)

        float pd[6] = {0.f, 0.f, 0.f, 0.f, 0.f, 0.f};
#pragma unroll
        for (int k = 0; k < 32; ++k)
#pragma unroll
            for (int d = 0; d < 6; ++d)
                pd[d] = fmaf(R[k], WOh[(k * 6 + d) * 16], pd[d]);
        // sum over the 16 h-lanes of this (b,n)
#pragma unroll
        for (int m = 1; m < 16; m <<= 1)
#pragma unroll
            for (int d = 0; d < 6; ++d)
                pd[d] += __shfl_xor(pd[d], m, 16);
        if ((tid & 15) == 0) {
            float* op = out + ((b * 256 + t) * 16 + n) * 6;
#pragma unroll
            for (int d = 0; d < 6; ++d) op[d] = xv[d] + bo[d] + pd[d];
        }
    }
}

extern "C" void kernel_launch(void* const* d_in, const int* in_sizes, int n_in,
                              void* d_out, int out_size, void* d_ws, size_t ws_size,
                              hipStream_t stream) {
    (void)in_sizes; (void)n_in; (void)out_size;
    const float* x     = (const float*)d_in[0];  // [16,256,16,6]
    const float* W_in  = (const float*)d_in[1];  // [6,512]
    const float* b_in  = (const float*)d_in[2];  // [512]
    const float* W_out = (const float*)d_in[3];  // [512,6]
    const float* b_out = (const float*)d_in[4];  // [6]
    float* out = (float*)d_out;                  // [16,256,16,6]
    float* Q   = (float*)d_ws;

    const size_t need32 = 4096UL * 32 * 32 * sizeof(float);  // 16 MB
    if (ws_size >= need32) {
        k_seg<32>  <<<512, 256, 0, stream>>>(x, W_in, b_in, Q);
        k_scan<32> <<<512, 256, 0, stream>>>(Q);
        k_apply<32><<<512, 256, 0, stream>>>(x, W_in, b_in, W_out, b_out, Q, out);
    } else {
        k_seg<16>  <<<256, 256, 0, stream>>>(x, W_in, b_in, Q);
        k_scan<16> <<<256, 256, 0, stream>>>(Q);
        k_apply<16><<<256, 256, 0, stream>>>(x, W_in, b_in, W_out, b_out, Q, out);
    }
}

// Round 3
// 216.640 us; speedup vs baseline: 1.8984x; 1.8984x over previous
//
#include <hip/hip_runtime.h>

// VersorRotorRNN: B=16, S=256, N=16, D=6, H=16, 32 blades (Cl(5,0)).
// Segmented parallel scan over S. normalize() is scale-invariant and the
// geometric product is bilinear+associative, so psi_t = N(dr_t (x) ... (x) dr_1)
// with dr unnormalized and all intermediate normalizations deferrable.
// SEGT segments of L=256/SEGT steps; Kogge-Stone in-wave scan over segments.
//
// R2 lesson: natural VGPR ~236; forcing min-waves=2 via __launch_bounds__
// spilled to scratch (FETCH 5MB->443MB). Keep (256,1); occupancy comes from
// grid (512 blocks = 2 blocks/CU; 236<=256 regs => 2 waves/SIMD resident).

#define EPS 1e-8f

// --- compile-time Cayley sign table: sgn(i,j) for C[i,j,i^j] ---
struct SgnTab { float v[32][32]; };
constexpr SgnTab make_sgn() {
    SgnTab t{};
    for (int i = 0; i < 32; ++i)
        for (int j = 0; j < 32; ++j) {
            int a = i >> 1, s = 0;
            while (a) {
                int x = a & j;
                while (x) { s += x & 1; x >>= 1; }
                a >>= 1;
            }
            t.v[i][j] = (s & 1) ? -1.0f : 1.0f;
        }
    return t;
}
__device__ constexpr SgnTab SG = make_sgn();

// dst = a (x) b (raw geometric product). dst may alias a or b.
__device__ __forceinline__ void gp_raw(float* __restrict__ dst,
                                       const float* a, const float* b) {
    float np[32];
#pragma unroll
    for (int k = 0; k < 32; ++k) np[k] = 0.0f;
#pragma unroll
    for (int i = 0; i < 32; ++i) {
#pragma unroll
        for (int j = 0; j < 32; ++j) {
            np[i ^ j] = fmaf(SG.v[i][j] * a[i], b[j], np[i ^ j]);
        }
    }
#pragma unroll
    for (int k = 0; k < 32; ++k) dst[k] = np[k];
}

__device__ __forceinline__ float inv_norm(const float* v) {
    float s0 = 0.f, s1 = 0.f, s2 = 0.f, s3 = 0.f;
#pragma unroll
    for (int k = 0; k < 32; k += 4) {
        s0 = fmaf(v[k],     v[k],     s0);
        s1 = fmaf(v[k + 1], v[k + 1], s1);
        s2 = fmaf(v[k + 2], v[k + 2], s2);
        s3 = fmaf(v[k + 3], v[k + 3], s3);
    }
    return rsqrtf((s0 + s1) + (s2 + s3) + EPS);
}

// LDS layouts (per-h, b128-friendly):
//   WIN: stride 196 floats/h: [h*196 + d*32 + c]   (196%32==4 -> 2-way banks, free;
//   BIN: stride  36 floats/h: [h*36 + c]            196%4==0 -> 16B aligned)
//   WOU: stride 196 floats/h: [h*196 + k*6 + d]
#define WIN_STRIDE 196
#define BIN_STRIDE 36

// build uu = b_in[h] + x_t . W_in[:,h*32..], uu[0]+=1  (all b128 LDS reads)
__device__ __forceinline__ void build_u(const float* __restrict__ W4h,
                                        const float* __restrict__ B4h,
                                        const float xv[6], float uu[32]) {
    const float4* B4 = (const float4*)B4h;
    const float4* W4 = (const float4*)W4h;
#pragma unroll
    for (int c4 = 0; c4 < 8; ++c4) {
        float4 bv = B4[c4];
        uu[4 * c4] = bv.x; uu[4 * c4 + 1] = bv.y;
        uu[4 * c4 + 2] = bv.z; uu[4 * c4 + 3] = bv.w;
    }
#pragma unroll
    for (int d = 0; d < 6; ++d) {
#pragma unroll
        for (int c4 = 0; c4 < 8; ++c4) {
            float4 wv = W4[d * 8 + c4];
            uu[4 * c4]     = fmaf(xv[d], wv.x, uu[4 * c4]);
            uu[4 * c4 + 1] = fmaf(xv[d], wv.y, uu[4 * c4 + 1]);
            uu[4 * c4 + 2] = fmaf(xv[d], wv.z, uu[4 * c4 + 2]);
            uu[4 * c4 + 3] = fmaf(xv[d], wv.w, uu[4 * c4 + 3]);
        }
    }
    uu[0] += 1.0f;  // delta_r (unnormalized; scale cancels)
}

// ---------------- pass 1: per-segment products -------------------
// thread u: h=u&15, bn=(u>>4)&255, s=u>>12. Raw product; normalize at store.
template <int SEGT>
__global__ __launch_bounds__(256, 1) void k_seg(
        const float* __restrict__ x, const float* __restrict__ W_in,
        const float* __restrict__ b_in, float* __restrict__ Q) {
    constexpr int L = 256 / SEGT;
    __shared__ float WL[16 * WIN_STRIDE];
    __shared__ float BL[16 * BIN_STRIDE];
    const int tid = threadIdx.x;
    for (int idx = tid; idx < 16 * WIN_STRIDE; idx += 256) {
        int h = idx / WIN_STRIDE, r = idx % WIN_STRIDE;
        if (r < 192) { int d = r >> 5, c = r & 31; WL[idx] = W_in[d * 512 + h * 32 + c]; }
    }
    for (int idx = tid; idx < 16 * BIN_STRIDE; idx += 256) {
        int h = idx / BIN_STRIDE, c = idx % BIN_STRIDE;
        if (c < 32) BL[idx] = b_in[h * 32 + c];
    }
    __syncthreads();

    const unsigned u = blockIdx.x * 256 + tid;
    const int h = u & 15, bn = (u >> 4) & 255, s = u >> 12;
    const int b = bn >> 4, n = bn & 15;
    const float* WLh = WL + h * WIN_STRIDE;
    const float* BLh = BL + h * BIN_STRIDE;

    float P[32];
    for (int i = 0; i < L; ++i) {
        const int t = s * L + i;
        const float2* xp = (const float2*)(x + ((b * 256 + t) * 16 + n) * 6);
        float2 x01 = xp[0], x23 = xp[1], x45 = xp[2];
        const float xv[6] = {x01.x, x01.y, x23.x, x23.y, x45.x, x45.y};
        float uu[32];
        build_u(WLh, BLh, xv, uu);
        if (i == 0) {
#pragma unroll
            for (int k = 0; k < 32; ++k) P[k] = uu[k];  // 1 (x) u = u
        } else {
            gp_raw(P, uu, P);    // raw; normalize deferred to store
        }
    }
    float rs = inv_norm(P);
    const int chain = bn * 16 + h;
    float4* qp = (float4*)(Q + (chain * SEGT + s) * 32);
#pragma unroll
    for (int r = 0; r < 8; ++r)
        qp[r] = make_float4(P[4 * r] * rs, P[4 * r + 1] * rs,
                            P[4 * r + 2] * rs, P[4 * r + 3] * rs);
}

// ---------------- pass 2: Kogge-Stone exclusive scan, in-wave ----------
// thread u: s = u & (SEGT-1), chain = u / SEGT. Raw combines; one final norm.
template <int SEGT>
__global__ __launch_bounds__(256, 1) void k_scan(float* __restrict__ Q) {
    const unsigned u = blockIdx.x * 256 + threadIdx.x;
    const int s = u & (SEGT - 1);
    const unsigned chain = u / SEGT;

    float xr[32];
    {
        const float4* qp = (const float4*)(Q + (chain * SEGT + s) * 32);
#pragma unroll
        for (int r = 0; r < 8; ++r) {
            float4 v = qp[r];
            xr[4 * r] = v.x; xr[4 * r + 1] = v.y;
            xr[4 * r + 2] = v.z; xr[4 * r + 3] = v.w;
        }
    }
#pragma unroll
    for (int k = 1; k < SEGT; k <<= 1) {
        float pr[32];
#pragma unroll
        for (int j = 0; j < 32; ++j) pr[j] = __shfl_up(xr[j], k, SEGT);
        if (s >= k) gp_raw(xr, xr, pr);  // later range on the left; no norm
    }
    {   // single normalization of the inclusive prefix
        float rs = inv_norm(xr);
#pragma unroll
        for (int j = 0; j < 32; ++j) xr[j] *= rs;
    }
    // exclusive shift by one within the SEGT-group
    float er[32];
#pragma unroll
    for (int j = 0; j < 32; ++j) er[j] = __shfl_up(xr[j], 1, SEGT);
    if (s == 0) {
#pragma unroll
        for (int j = 0; j < 32; ++j) er[j] = 0.0f;
        er[0] = 1.0f;  // identity rotor
    }
    float4* qp = (float4*)(Q + (chain * SEGT + s) * 32);
#pragma unroll
    for (int r = 0; r < 8; ++r)
        qp[r] = make_float4(er[4 * r], er[4 * r + 1],
                            er[4 * r + 2], er[4 * r + 3]);
}

// ---------------- pass 3: apply interior + project + write output ----------
template <int SEGT>
__global__ __launch_bounds__(256, 1) void k_apply(
        const float* __restrict__ x, const float* __restrict__ W_in,
        const float* __restrict__ b_in, const float* __restrict__ W_out,
        const float* __restrict__ b_out, const float* __restrict__ Pre,
        float* __restrict__ out) {
    constexpr int L = 256 / SEGT;
    __shared__ float WL[16 * WIN_STRIDE];
    __shared__ float BL[16 * BIN_STRIDE];
    __shared__ float WO[16 * WIN_STRIDE];  // [h*196 + k*6 + d]
    const int tid = threadIdx.x;
    for (int idx = tid; idx < 16 * WIN_STRIDE; idx += 256) {
        int h = idx / WIN_STRIDE, r = idx % WIN_STRIDE;
        if (r < 192) {
            int d = r >> 5, c = r & 31;
            WL[idx] = W_in[d * 512 + h * 32 + c];
            WO[idx] = W_out[h * 192 + r];   // (h*32+k)*6+d == h*192 + (k*6+d)
        }
    }
    for (int idx = tid; idx < 16 * BIN_STRIDE; idx += 256) {
        int h = idx / BIN_STRIDE, c = idx % BIN_STRIDE;
        if (c < 32) BL[idx] = b_in[h * 32 + c];
    }
    __syncthreads();

    const unsigned u = blockIdx.x * 256 + tid;
    const int h = u & 15, bn = (u >> 4) & 255, s = u >> 12;
    const int b = bn >> 4, n = bn & 15;
    const int chain = bn * 16 + h;
    const float* WLh = WL + h * WIN_STRIDE;
    const float* BLh = BL + h * BIN_STRIDE;
    const float4* WO4 = (const float4*)(WO + h * WIN_STRIDE);

    float R[32];
    {
        const float4* pp = (const float4*)(Pre + (chain * SEGT + s) * 32);
#pragma unroll
        for (int r = 0; r < 8; ++r) {
            float4 v = pp[r];
            R[4 * r] = v.x; R[4 * r + 1] = v.y;
            R[4 * r + 2] = v.z; R[4 * r + 3] = v.w;
        }
    }
    float bo[6];
#pragma unroll
    for (int d = 0; d < 6; ++d) bo[d] = b_out[d];

    for (int i = 0; i < L; ++i) {
        const int t = s * L + i;
        const float2* xp = (const float2*)(x + ((b * 256 + t) * 16 + n) * 6);
        float2 x01 = xp[0], x23 = xp[1], x45 = xp[2];
        const float xv[6] = {x01.x, x01.y, x23.x, x23.y, x45.x, x45.y};
        float uu[32];
        build_u(WLh, BLh, xv, uu);
        gp_raw(R, uu, R);            // raw psi_t (unnormalized)
        float rs = inv_norm(R);      // fold normalization into pd

        float pd[6] = {0.f, 0.f, 0.f, 0.f, 0.f, 0.f};
#pragma unroll
        for (int c4 = 0; c4 < 48; ++c4) {
            float4 w = WO4[c4];
            pd[(4 * c4 + 0) % 6] = fmaf(R[(4 * c4 + 0) / 6], w.x, pd[(4 * c4 + 0) % 6]);
            pd[(4 * c4 + 1) % 6] = fmaf(R[(4 * c4 + 1) / 6], w.y, pd[(4 * c4 + 1) % 6]);
            pd[(4 * c4 + 2) % 6] = fmaf(R[(4 * c4 + 2) / 6], w.z, pd[(4 * c4 + 2) % 6]);
            pd[(4 * c4 + 3) % 6] = fmaf(R[(4 * c4 + 3) / 6], w.w, pd[(4 * c4 + 3) % 6]);
        }
        // sum over the 16 h-lanes of this (b,n); scale by rs (psi normalization)
#pragma unroll
        for (int d = 0; d < 6; ++d) pd[d] *= rs;
#pragma unroll
        for (int m = 1; m < 16; m <<= 1)
#pragma unroll
            for (int d = 0; d < 6; ++d)
                pd[d] += __shfl_xor(pd[d], m, 16);
        if ((tid & 15) == 0) {
            float* op = out + ((b * 256 + t) * 16 + n) * 6;
#pragma unroll
            for (int d = 0; d < 6; ++d) op[d] = xv[d] + bo[d] + pd[d];
        }
    }
}

extern "C" void kernel_launch(void* const* d_in, const int* in_sizes, int n_in,
                              void* d_out, int out_size, void* d_ws, size_t ws_size,
                              hipStream_t stream) {
    (void)in_sizes; (void)n_in; (void)out_size;
    const float* x     = (const float*)d_in[0];  // [16,256,16,6]
    const float* W_in  = (const float*)d_in[1];  // [6,512]
    const float* b_in  = (const float*)d_in[2];  // [512]
    const float* W_out = (const float*)d_in[3];  // [512,6]
    const float* b_out = (const float*)d_in[4];  // [6]
    float* out = (float*)d_out;                  // [16,256,16,6]
    float* Q   = (float*)d_ws;

    const size_t need32 = 4096UL * 32 * 32 * sizeof(float);  // 16 MB
    if (ws_size >= need32) {
        k_seg<32>  <<<512, 256, 0, stream>>>(x, W_in, b_in, Q);
        k_scan<32> <<<512, 256, 0, stream>>>(Q);
        k_apply<32><<<512, 256, 0, stream>>>(x, W_in, b_in, W_out, b_out, Q, out);
    } else {
        k_seg<16>  <<<256, 256, 0, stream>>>(x, W_in, b_in, Q);
        k_scan<16> <<<256, 256, 0, stream>>>(Q);
        k_apply<16><<<256, 256, 0, stream>>>(x, W_in, b_in, W_out, b_out, Q, out);
    }
}